// Round 4
// baseline (2833.757 us; speedup 1.0000x reference)
//
// R13: stagger two independent chains per group. The 4 samples/group are
// independent GRU recurrences; R12 lockstepped them so the full sync chain
// (publish-drain -> flag visible -> poll DETECT on last-of-32 -> gather) sat
// on the critical path every step (~7.4us measured vs ~1.2us compute). Split:
// chain A = samples {0,1}, chain B = {2,3}, each with its own hF buffers +
// flags, alternating phases A(s),B(s),A(s+1),... When I poll chain A, every
// partner set flagA a whole phase-B ago (~2us) -> detect latency hides under
// the other chain's work; step cost collapses toward pure phase work.
// Per-chain sync protocol is byte-identical to proven R12 (flag stored by
// tid0 after __syncthreads drains publish stores; poll+gather both sc1;
// my flag s+1 set only after my parity-s gather => WAR safe; prep seeds
// buf0 + zeroes flags => no cross-run staleness). Compute math per sample
// is bit-identical to R12 (same fmaf order, same shfl reduce, same gates).
#include <hip/hip_runtime.h>
#include <cstdint>
#include <cstddef>

#define H    768
#define G3   2304
#define TT   512
#define BS   32
#define NGRP 8
#define GWG  32        // worker WGs per group (one per CU on the XCD)
#define SPG  4         // samples per group
#define GRID_GRU 2048  // oversubscribed; ticket winners persist

// dynamic LDS pad: static ~14KB + 69632 > 81920 => 1 WG/CU
#define LDS_PAD  69632

// ctrl block inside xg dead zone (b=0, t>=384; L[0]~256 => never touched)
#define WS_XG    0
#define WS_CTRL  3538944                 // byte offset of xg[0][384][0]
#define CT_TICK  0                       // uint[8]
#define CT_FLAGS 64                      // uint[2][8][32] = 2048 B
#define CT_L     2112                    // int[32]
#define CT_HB    2240                    // float[8][2 chain][2 par][1536] = 196608 B

typedef float vf4 __attribute__((ext_vector_type(4)));

// ---------------- phase 1: lengths + tickets/flags + hF buf0 seed -------------
__global__ void prep_kernel(const int* __restrict__ mask, const float* __restrict__ gc,
                            int* __restrict__ L, unsigned int* __restrict__ tick,
                            unsigned int* __restrict__ flags,
                            float* __restrict__ hF) {
    __shared__ int sbuf[256];
    const int b = blockIdx.x, tid = threadIdx.x;
    int c = 0;
    for (int t = tid; t < TT; t += 256) c += (mask[b * TT + t] != 0) ? 1 : 0;
    sbuf[tid] = c;
    __syncthreads();
    for (int off = 128; off > 0; off >>= 1) {
        if (tid < off) sbuf[tid] += sbuf[tid + off];
        __syncthreads();
    }
    if (tid == 0) {
        int l = sbuf[0];
        if (l < 1) l = 2;              // reference: where(L<1, 2, L)
        L[b] = l;
    }
    if (b == 0 && tid < NGRP) tick[tid] = 0u;
    if (tid < 16) flags[b * 16 + tid] = 0u;        // 32 blocks x 16 = 512
    // seed parity0 of both chains: hF[g][chain][0][coord*2+smp] = gc[coord]
    // 8 g x 2 chain x 1536 = 24576 floats, 768 per block
    for (int i = tid; i < 768; i += 256) {
        const int e = b * 768 + i;                 // 0..24575
        const int g = e / 3072, r = e - g * 3072;  // r in [0,3072)
        const int chain = r / 1536, idx = r - chain * 1536;
        hF[g * 6144 + chain * 3072 + idx] = gc[idx >> 1];
    }
}

// ---------------- phase 2: xg = emb @ W_ih^T + b_ih (unchanged) ----------------
__global__ __launch_bounds__(256) void xg_gemm(
    const float* __restrict__ A, const float* __restrict__ W,
    const float* __restrict__ bih, const int* __restrict__ L,
    float* __restrict__ xg)
{
    const int mt = blockIdx.x, nt = blockIdx.y;
    const int b  = mt >> 3;
    const int t0 = (mt & 7) << 6;
    if (t0 >= L[b]) return;

    __shared__ __align__(16) float As[16][68];
    __shared__ __align__(16) float Bsh[16][68];

    const int tid = threadIdx.x;
    const int m0 = mt << 6, n0 = nt << 6;
    const int lr = tid >> 2;
    const int lk = (tid & 3) << 2;
    const int tm = (tid >> 4) << 2;
    const int tn = (tid & 15) << 2;

    float c[4][4] = {};
    const float* Ap = A + (size_t)(m0 + lr) * H + lk;
    const float* Wp = W + (size_t)(n0 + lr) * H + lk;

    for (int k0 = 0; k0 < H; k0 += 16) {
        float4 av = *(const float4*)(Ap + k0);
        float4 bv = *(const float4*)(Wp + k0);
        As[lk + 0][lr] = av.x; As[lk + 1][lr] = av.y;
        As[lk + 2][lr] = av.z; As[lk + 3][lr] = av.w;
        Bsh[lk + 0][lr] = bv.x; Bsh[lk + 1][lr] = bv.y;
        Bsh[lk + 2][lr] = bv.z; Bsh[lk + 3][lr] = bv.w;
        __syncthreads();
#pragma unroll
        for (int kk = 0; kk < 16; ++kk) {
            float4 a4 = *(const float4*)&As[kk][tm];
            float4 b4 = *(const float4*)&Bsh[kk][tn];
            c[0][0] = fmaf(a4.x, b4.x, c[0][0]); c[0][1] = fmaf(a4.x, b4.y, c[0][1]);
            c[0][2] = fmaf(a4.x, b4.z, c[0][2]); c[0][3] = fmaf(a4.x, b4.w, c[0][3]);
            c[1][0] = fmaf(a4.y, b4.x, c[1][0]); c[1][1] = fmaf(a4.y, b4.y, c[1][1]);
            c[1][2] = fmaf(a4.y, b4.z, c[1][2]); c[1][3] = fmaf(a4.y, b4.w, c[1][3]);
            c[2][0] = fmaf(a4.z, b4.x, c[2][0]); c[2][1] = fmaf(a4.z, b4.y, c[2][1]);
            c[2][2] = fmaf(a4.z, b4.z, c[2][2]); c[2][3] = fmaf(a4.z, b4.w, c[2][3]);
            c[3][0] = fmaf(a4.w, b4.x, c[3][0]); c[3][1] = fmaf(a4.w, b4.y, c[3][1]);
            c[3][2] = fmaf(a4.w, b4.z, c[3][2]); c[3][3] = fmaf(a4.w, b4.w, c[3][3]);
        }
        __syncthreads();
    }
    const float4 bias = *(const float4*)&bih[n0 + tn];
#pragma unroll
    for (int i = 0; i < 4; ++i) {
        float4 o;
        o.x = c[i][0] + bias.x; o.y = c[i][1] + bias.y;
        o.z = c[i][2] + bias.z; o.w = c[i][3] + bias.w;
        *(float4*)&xg[(size_t)(m0 + tm + i) * G3 + n0 + tn] = o;
    }
}

// ---------------- one chain-phase of the staggered GRU ----------------
__device__ __forceinline__ void gru_phase(
    const int s, const int tid, const int kc, const int q, const int wgl,
    const int cgl, const int Lb, const int boff,
    const float bR, const float bZ, const float bN,
    const float* __restrict__ xb, const float (&w)[9][24],
    float* hl, float* sred,
    float* hfx, unsigned int* flg, float* __restrict__ out)
{
    // xg loads issued first: HBM/L3 latency hides under poll + gather
    float xr = 0.f, xz = 0.f, xn = 0.f;
    if (tid < 48) {
        const int tt = (s < Lb) ? s : (Lb - 1);
        const float* xp = xb + (size_t)tt * G3;
        xr = xp[0]; xz = xp[H]; xn = xp[2 * H];
    }

    // damper: wave0 polls 32 flags >= s. With staggering, partners set this
    // flag a whole other-chain phase ago -> expected to pass on first try.
    if (s && tid < 64) {
        const unsigned int* fp = flg + (tid & 31);
        int spins = 0;
        for (;;) {
            unsigned int v;
            asm volatile("global_load_dword %0, %1, off sc1\n\t"
                         "s_waitcnt vmcnt(0)"
                         : "=v"(v) : "v"(fp) : "memory");
            if (__all((int)v >= s)) break;
            if (((++spins) & 63) == 0) {          // belt-and-suspenders valve
                v = __hip_atomic_load(fp, __ATOMIC_RELAXED,
                                      __HIP_MEMORY_SCOPE_AGENT);
                if (__all((int)v >= s)) break;
            }
            if (spins > 4) __builtin_amdgcn_s_sleep(1);
        }
    }
    __syncthreads();

    // gather 1536 f32 (chain buffer, parity s&1): 384 dwordx4 per WG, once.
    {
        const float* hr0 = hfx + (s & 1) * 1536 + 4 * tid;
        vf4 a0, a1;
        if (tid < 128) {                           // waves 0,1: 2 requests
            const float* hr1 = hr0 + 1024;
            asm volatile(
                "global_load_dwordx4 %0, %2, off sc1\n\t"
                "global_load_dwordx4 %1, %3, off sc1\n\t"
                "s_waitcnt vmcnt(0)"
                : "=&v"(a0), "=&v"(a1) : "v"(hr0), "v"(hr1) : "memory");
            *(vf4*)&hl[4 * tid] = a0;
            *(vf4*)&hl[4 * tid + 1024] = a1;
        } else {                                   // waves 2,3: 1 request
            asm volatile(
                "global_load_dwordx4 %0, %1, off sc1\n\t"
                "s_waitcnt vmcnt(0)"
                : "=&v"(a0) : "v"(hr0) : "memory");
            *(vf4*)&hl[4 * tid] = a0;
        }
    }
    __syncthreads();                               // syncA: h in LDS

    float hp = 0.f;
    if (tid < 48) hp = hl[cgl * 2 + (tid & 1)];

    // dot: 24 x (ds_read_b64 + 18 fma)  [per-sample fmaf order == R12]
    float acc[9][2] = {};
#pragma unroll
    for (int ki = 0; ki < 24; ++ki) {
        const float2 h2 = *(const float2*)&hl[(kc + (ki << 5)) * 2];
#pragma unroll
        for (int j = 0; j < 9; ++j) {
            const float wv = w[j][ki];
            acc[j][0] = fmaf(wv, h2.x, acc[j][0]);
            acc[j][1] = fmaf(wv, h2.y, acc[j][1]);
        }
    }
    // reduce over kc (xor 1..16 stays in 32-lane half)
#pragma unroll
    for (int j = 0; j < 9; ++j)
#pragma unroll
        for (int m = 0; m < 2; ++m) {
            float x = acc[j][m];
            x += __shfl_xor(x, 1);
            x += __shfl_xor(x, 2);
            x += __shfl_xor(x, 4);
            x += __shfl_xor(x, 8);
            x += __shfl_xor(x, 16);
            acc[j][m] = x;
        }
    if (kc == 0) {
#pragma unroll
        for (int j = 0; j < 9; ++j) {
            sred[(q * 9 + j) * 3 + 0] = acc[j][0];
            sred[(q * 9 + j) * 3 + 1] = acc[j][1];
        }
    }
    __syncthreads();                               // syncB

    // gates + publish (plain f32 workgroup-scope stores: L2-resident)
    float* hw = hfx + ((s + 1) & 1) * 1536;
    if (tid < 48) {
        const int c = tid >> 1, smp = tid & 1;
        const float sr = sred[c * 3 + smp]        + bR;
        const float sz = sred[(24 + c) * 3 + smp] + bZ;
        const float sn = sred[(48 + c) * 3 + smp] + bN;
        const float rg = 1.f / (1.f + expf(-(xr + sr)));
        const float zg = 1.f / (1.f + expf(-(xz + sz)));
        const float ng = tanhf(xn + rg * sn);
        const float hn = (s < Lb) ? ((1.f - zg) * ng + zg * hp) : hp;
        __hip_atomic_store(&hw[cgl * 2 + smp], hn, __ATOMIC_RELAXED,
                           __HIP_MEMORY_SCOPE_WORKGROUP);
        if (s == Lb - 1) {
            const int bb = boff + smp;
            out[bb * H + cgl] = hn;                   // outputs[bb]
            if (bb == BS - 1) out[BS * H + cgl] = hn; // hF == outputs[31]
        }
    }
    __syncthreads();    // drains publish stores (vmcnt(0) before s_barrier)
    if (tid == 0)
        __hip_atomic_store(&flg[wgl], (unsigned int)(s + 1),
                           __ATOMIC_RELAXED, __HIP_MEMORY_SCOPE_WORKGROUP);
}

// ---------------- phase 3: per-XCD group of 32 WGs, 2 staggered chains -------
__global__ __launch_bounds__(256, 1) void gru_kernel(
    const float* __restrict__ Whh, const float* __restrict__ bhh,
    const float* __restrict__ xg, const int* __restrict__ L,
    unsigned int* tick, unsigned int* flags, float* hF,
    float* __restrict__ out)
{
    extern __shared__ char lds_occupancy_pad[];   // forces 1 WG/CU
    (void)lds_occupancy_pad;

    unsigned int xcc;
    asm volatile("s_getreg_b32 %0, hwreg(HW_REG_XCC_ID)" : "=s"(xcc));
    const int g = (int)xcc;               // group = physical XCD 0..7

    __shared__ int s_wg;
    const int tid = threadIdx.x;
    if (tid == 0)
        s_wg = (int)__hip_atomic_fetch_add(&tick[g], 1u, __ATOMIC_RELAXED,
                                           __HIP_MEMORY_SCOPE_AGENT);
    __syncthreads();
    const int wgl = s_wg;
    if (wgl >= GWG) return;               // 32 workers per XCD

    __shared__ __align__(16) float hA_lds[1536];   // [coord][2 smp]
    __shared__ __align__(16) float hB_lds[1536];
    __shared__ float sredA[72 * 3];                // [row][2 smp + pad]
    __shared__ float sredB[72 * 3];
    __shared__ int LsS[SPG];

    unsigned int* flgA = flags +       g * GWG;
    unsigned int* flgB = flags + 256 + g * GWG;
    float* hFA = hF + (size_t)g * 6144;
    float* hFB = hFA + 3072;

    if (tid < SPG) LsS[tid] = L[g * SPG + tid];
    __syncthreads();
    const int S_A = max(LsS[0], LsS[1]);
    const int S_B = max(LsS[2], LsS[3]);
    const int S   = max(S_A, S_B);

    const int q = tid >> 5, kc = tid & 31;

    // weights -> VGPRs: w[j][ki] = Whh[row(q*9+j)][kc+32*ki]  (unchanged)
    float w[9][24];
#pragma unroll
    for (int j = 0; j < 9; ++j) {
        const int lr = q * 9 + j;
        const int row = (lr / 24) * H + 24 * wgl + (lr % 24);
        const float* wp = Whh + (size_t)row * H + kc;
#pragma unroll
        for (int ki = 0; ki < 24; ++ki) w[j][ki] = wp[ki << 5];
    }

    // gate-thread constants (tid<48: coord c=tid>>1, sample smp=tid&1)
    const int cgl = 24 * wgl + (tid >> 1);         // valid/used only tid<48
    float bR = 0.f, bZ = 0.f, bN = 0.f;
    int LbA = 2, LbB = 2;
    const float* xbA = xg;
    const float* xbB = xg;
    if (tid < 48) {
        const int smp = tid & 1;
        bR = bhh[cgl]; bZ = bhh[H + cgl]; bN = bhh[2 * H + cgl];
        LbA = LsS[smp];
        LbB = LsS[2 + smp];
        xbA = xg + (size_t)(g * SPG + smp)     * TT * G3 + cgl;
        xbB = xg + (size_t)(g * SPG + 2 + smp) * TT * G3 + cgl;
    }

    for (int s = 0; s < S; ++s) {
        if (s < S_A)
            gru_phase(s, tid, kc, q, wgl, cgl, LbA, g * SPG + 0,
                      bR, bZ, bN, xbA, w, hA_lds, sredA, hFA, flgA, out);
        if (s < S_B)
            gru_phase(s, tid, kc, q, wgl, cgl, LbB, g * SPG + 2,
                      bR, bZ, bN, xbB, w, hB_lds, sredB, hFB, flgB, out);
    }
}

extern "C" void kernel_launch(void* const* d_in, const int* in_sizes, int n_in,
                              void* d_out, int out_size, void* d_ws, size_t ws_size,
                              hipStream_t stream) {
    const float* emb  = (const float*)d_in[0];   // [32][512][768]
    const int*   mask = (const int*)d_in[1];     // [32][512]
    const float* gctx = (const float*)d_in[2];   // [1][1][768]
    const float* Wih  = (const float*)d_in[3];   // [2304][768]
    const float* Whh  = (const float*)d_in[4];   // [2304][768]
    const float* bih  = (const float*)d_in[5];   // [2304]
    const float* bhh  = (const float*)d_in[6];   // [2304]
    float* out = (float*)d_out;                  // 32*768 + 768 floats

    char* ws = (char*)d_ws;
    float*              xg    = (float*)(ws + WS_XG);
    char*               ctrl  = ws + WS_CTRL;
    unsigned int*       tick  = (unsigned int*)(ctrl + CT_TICK);
    unsigned int*       flags = (unsigned int*)(ctrl + CT_FLAGS);
    int*                L     = (int*)(ctrl + CT_L);
    float*              hF    = (float*)(ctrl + CT_HB);

    prep_kernel<<<BS, 256, 0, stream>>>(mask, gctx, L, tick, flags, hF);
    xg_gemm<<<dim3(256, 36), 256, 0, stream>>>(emb, Wih, bih, L, xg);
    gru_kernel<<<GRID_GRU, 256, LDS_PAD, stream>>>(Whh, bhh, xg, L, tick, flags, hF, out);
}